// Round 10
// baseline (231.906 us; speedup 1.0000x reference)
//
#include <hip/hip_runtime.h>
#include <hip/hip_bf16.h>
#include <math.h>

// Fixed dims: B=2, T=384, C=768 -> M = 768. NH=384, HD=2. SCALE = 1/sqrt(2).
#define SCALE_QK 0.70710678118654752f
#define PSTRIDE 589824     // 768*768 (split-K partial stride, floats)

typedef __attribute__((ext_vector_type(8))) short bf16x8;   // 8 bf16 = 4 VGPRs
typedef __attribute__((ext_vector_type(4))) float floatx4;

__device__ __forceinline__ void gload16(const void* g, void* l) {
  __builtin_amdgcn_global_load_lds(
      (const __attribute__((address_space(1))) void*)g,
      (__attribute__((address_space(3))) void*)l, 16, 0, 0);
}

__device__ __forceinline__ float bf2f(unsigned short u) {
  union { float f; unsigned int i; } c; c.i = ((unsigned int)u) << 16; return c.f;
}

__device__ __forceinline__ float gelu_f(float v) {
  return 0.5f * v * (1.f + erff(v * 0.70710678118654752f));
}

struct MegaArgs {
  const float *x, *Wq, *bq, *Wp, *bp, *g1, *be1, *g2, *be2, *W1, *b1, *W2, *b2;
  __hip_bfloat16 *h1, *qkvb, *yb, *h2, *ff1b, *Tq, *Tp, *T1, *T2;
  float *x2, *part, *out;
  int *cnt;   // [0..11] proj row-panels, [12..155] ff2 tiles
};

// ---------------------------------------------------------------------------
// Weight transpose+convert tile: fp32 [K][N] -> bf16 [N][K], one 32x32 tile.
// ---------------------------------------------------------------------------
__device__ __forceinline__ void wconv_seg(const float* __restrict__ src,
                                          __hip_bfloat16* __restrict__ dst,
                                          int K, int N, int idx, char* smem) {
  float (*t)[33] = (float(*)[33])smem;
  int tilesN = N >> 5;
  int tk = idx / tilesN, tn = idx - tk * tilesN;
  int r = threadIdx.x >> 5, c = threadIdx.x & 31;
#pragma unroll
  for (int p = 0; p < 4; ++p)
    t[p * 8 + r][c] = src[(size_t)(tk * 32 + p * 8 + r) * N + tn * 32 + c];
  __syncthreads();
#pragma unroll
  for (int p = 0; p < 4; ++p)
    dst[(size_t)(tn * 32 + p * 8 + r) * K + tk * 32 + c] =
        __float2bfloat16(t[c][p * 8 + r]);
}

// ---------------------------------------------------------------------------
// Generic LN row (256 threads, one row): dst = LN(src; g, b) in bf16.
// ---------------------------------------------------------------------------
__device__ __forceinline__ void ln_row(const float* __restrict__ src,
                                       const float* __restrict__ g,
                                       const float* __restrict__ b,
                                       __hip_bfloat16* __restrict__ dst,
                                       int r, char* smem) {
  float* red0 = (float*)smem; float* red1 = red0 + 4;
  const float* xr = src + (size_t)r * 768;
  __hip_bfloat16* orow = dst + (size_t)r * 768;
  float vals[3]; float s = 0.f, s2 = 0.f;
#pragma unroll
  for (int p = 0; p < 3; ++p) {
    float v = xr[threadIdx.x + p * 256];
    vals[p] = v; s += v; s2 += v * v;
  }
#pragma unroll
  for (int off = 32; off > 0; off >>= 1) {
    s += __shfl_down(s, off); s2 += __shfl_down(s2, off);
  }
  int wid = threadIdx.x >> 6, lane = threadIdx.x & 63;
  if (lane == 0) { red0[wid] = s; red1[wid] = s2; }
  __syncthreads();
  if (threadIdx.x == 0) {
    red0[0] = red0[0] + red0[1] + red0[2] + red0[3];
    red1[0] = red1[0] + red1[1] + red1[2] + red1[3];
  }
  __syncthreads();
  float mean = red0[0] * (1.f / 768), var = red1[0] * (1.f / 768) - mean * mean;
  float rstd = rsqrtf(var + 1e-5f);
#pragma unroll
  for (int p = 0; p < 3; ++p) {
    int i = threadIdx.x + p * 256;
    orow[i] = __float2bfloat16((vals[p] - mean) * rstd * g[i] + b[i]);
  }
}

// ---------------------------------------------------------------------------
// LN of a 64-row panel by ONE block (256 thr, 4 thr/row, shfl_xor reduce).
// h2[rows bm..bm+63] = LN(x2; g2, be2).
// ---------------------------------------------------------------------------
__device__ __forceinline__ void ln_panel(const MegaArgs& a, int bm) {
  const int sub = threadIdx.x & 3;            // 0..3, 192 cols each
  const int row = bm + (threadIdx.x >> 2);    // 64 rows
  const float* xr = a.x2 + (size_t)row * 768 + sub * 192;
  float s = 0.f, s2 = 0.f;
#pragma unroll
  for (int i = 0; i < 48; ++i) {
    floatx4 v = *(const floatx4*)(xr + i * 4);
#pragma unroll
    for (int e = 0; e < 4; ++e) { s += v[e]; s2 += v[e] * v[e]; }
  }
  s += __shfl_xor(s, 1); s2 += __shfl_xor(s2, 1);
  s += __shfl_xor(s, 2); s2 += __shfl_xor(s2, 2);
  float mean = s * (1.f / 768), var = s2 * (1.f / 768) - mean * mean;
  float rstd = rsqrtf(var + 1e-5f);
  __hip_bfloat16* orow = a.h2 + (size_t)row * 768 + sub * 192;
  const float* g = a.g2 + sub * 192;
  const float* b = a.be2 + sub * 192;
#pragma unroll
  for (int i = 0; i < 48; ++i) {
    floatx4 v = *(const floatx4*)(xr + i * 4);
#pragma unroll
    for (int e = 0; e < 4; ++e)
      orow[i * 4 + e] =
          __float2bfloat16((v[e] - mean) * rstd * g[i * 4 + e] + b[i * 4 + e]);
  }
}

// ---------------------------------------------------------------------------
// ff2 final epilogue for one 64x64 tile by ONE block:
// out = x2 + gelu(sum4 part + b2).
// ---------------------------------------------------------------------------
__device__ __forceinline__ void ff2_finish(const MegaArgs& a, int bm, int bn) {
#pragma unroll
  for (int q = 0; q < 4; ++q) {
    int e4 = q * 256 + threadIdx.x;       // float4 index within tile (0..1023)
    int r = e4 >> 4, c4 = e4 & 15;        // 16 float4 per 64-col row
    size_t off = (size_t)(bm + r) * 768 + bn + c4 * 4;
    floatx4 s = *(const floatx4*)(a.part + off);
    s += *(const floatx4*)(a.part + PSTRIDE + off);
    s += *(const floatx4*)(a.part + 2 * (size_t)PSTRIDE + off);
    s += *(const floatx4*)(a.part + 3 * (size_t)PSTRIDE + off);
    floatx4 bv = *(const floatx4*)(a.b2 + bn + c4 * 4);
    floatx4 xv = *(const floatx4*)(a.x2 + off);
    floatx4 o;
#pragma unroll
    for (int e = 0; e < 4; ++e) o[e] = xv[e] + gelu_f(s[e] + bv[e]);
    *(floatx4*)(a.out + off) = o;
  }
}

// ---------------------------------------------------------------------------
// bf16 MFMA GEMM tile (round-3 proven, 5x refcheck'd). 64x64, BK=64, depth-2
// pipeline over 3 LDS buffers, counted vmcnt, XOR swizzle on source+read
// (dest linear). SPLIT: raw fp32 partial (N cols); else bias (+gelu)(+res).
// ---------------------------------------------------------------------------
template <int NT, bool GELU, bool RES, bool OUT_BF16, bool SPLIT>
__device__ __forceinline__ void gemm_tile(
    const __hip_bfloat16* __restrict__ A, int ldA,
    const __hip_bfloat16* __restrict__ Bt, int ldB,
    const float* __restrict__ bias, const float* __restrict__ res,
    void* __restrict__ outp, int N, int bm, int bn, int kofe, char* lds) {
  const int tid = threadIdx.x;
  const int w = tid >> 6, l = tid & 63;

  const int sr = (w << 3) + (l >> 3);                   // 0..31
  const int swb = ((l & 7) << 4) ^ ((l >> 3) << 4);     // byte within 128B row
  const char* a0 = (const char*)(A + (size_t)(bm + sr) * ldA + kofe) + swb;
  const char* a1 = a0 + (size_t)32 * ldA * 2;
  const char* b0 = (const char*)(Bt + (size_t)(bn + sr) * ldB + kofe) + swb;
  const char* b1 = b0 + (size_t)32 * ldB * 2;
  char* dW = lds + (w << 10);

#define STAGE(buf, t) do {                     \
    char* d_ = dW + (buf) * 16384;             \
    gload16(a0 + (t) * 128, d_);               \
    gload16(a1 + (t) * 128, d_ + 4096);        \
    gload16(b0 + (t) * 128, d_ + 8192);        \
    gload16(b1 + (t) * 128, d_ + 12288);       \
  } while (0)

  const int wr = w >> 1, wc = w & 1;
  const int fr = l & 15, g = l >> 4;
  const int fsw = (fr & 7) << 4;
  int aof[2][2], bof[2][2];
#pragma unroll
  for (int i = 0; i < 2; ++i)
#pragma unroll
    for (int kk = 0; kk < 2; ++kk) {
      aof[i][kk] = (wr * 32 + i * 16 + fr) * 128 + ((kk * 64 + g * 16) ^ fsw);
      bof[i][kk] = 8192 + (wc * 32 + i * 16 + fr) * 128 +
                   ((kk * 64 + g * 16) ^ fsw);
    }

  floatx4 acc[2][2] = {};

#define COMPUTE(bufoff) do {                                          \
    const char* base_ = lds + (bufoff);                               \
    bf16x8 av_[2][2], bv_[2][2];                                      \
    _Pragma("unroll") for (int i = 0; i < 2; ++i)                     \
      _Pragma("unroll") for (int kk = 0; kk < 2; ++kk) {              \
        av_[i][kk] = *(const bf16x8*)(base_ + aof[i][kk]);            \
        bv_[i][kk] = *(const bf16x8*)(base_ + bof[i][kk]);            \
      }                                                               \
    _Pragma("unroll") for (int kk = 0; kk < 2; ++kk)                  \
      _Pragma("unroll") for (int i = 0; i < 2; ++i)                   \
        _Pragma("unroll") for (int j = 0; j < 2; ++j)                 \
          acc[i][j] = __builtin_amdgcn_mfma_f32_16x16x32_bf16(        \
              av_[i][kk], bv_[j][kk], acc[i][j], 0, 0, 0);            \
  } while (0)

  STAGE(0, 0);
  STAGE(1, 1);
  asm volatile("s_waitcnt vmcnt(4)" ::: "memory");
  __builtin_amdgcn_s_barrier();
  asm volatile("" ::: "memory");

#pragma unroll
  for (int t = 0; t < NT; ++t) {
    if (t + 2 < NT) STAGE((t + 2) % 3, t + 2);
    COMPUTE((t % 3) * 16384);
    if (t + 1 < NT) {
      if (t + 2 < NT) {
        asm volatile("s_waitcnt vmcnt(4)" ::: "memory");
      } else {
        asm volatile("s_waitcnt vmcnt(0)" ::: "memory");
      }
      __builtin_amdgcn_s_barrier();
      asm volatile("" ::: "memory");
    }
  }
#undef STAGE
#undef COMPUTE

  // C/D: col = lane&15, row = (lane>>4)*4 + reg (m89)
  const int orow0 = bm + wr * 32 + g * 4;
  const int ocol0 = bn + wc * 32 + fr;
#pragma unroll
  for (int fm = 0; fm < 2; ++fm)
#pragma unroll
    for (int fn = 0; fn < 2; ++fn) {
      int col = ocol0 + fn * 16;
      float bv = SPLIT ? 0.f : bias[col];
#pragma unroll
      for (int i = 0; i < 4; ++i) {
        int row = orow0 + fm * 16 + i;
        if (SPLIT) {
          ((float*)outp)[(size_t)row * N + col] = acc[fm][fn][i];
        } else {
          float v = acc[fm][fn][i] + bv;
          if (GELU) v = gelu_f(v);
          if (RES) v += res[(size_t)row * N + col];
          if (OUT_BF16)
            ((__hip_bfloat16*)outp)[(size_t)row * N + col] = __float2bfloat16(v);
          else
            ((float*)outp)[(size_t)row * N + col] = v;
        }
      }
    }
}

// ---------------------------------------------------------------------------
// Attention token (256 threads): rows t and 383-t (t<128) -> balanced 385
// iters/thread. Scores over head axis, causal m<=n, plain exp (bounded data).
// ---------------------------------------------------------------------------
__device__ __forceinline__ void attn_row(int n, const ushort2* base,
    const float2* ks, const float2* vs, __hip_bfloat16* yrow) {
  ushort2 qu = base[n];
  float q0 = bf2f(qu.x) * SCALE_QK, q1 = bf2f(qu.y) * SCALE_QK;
  float sm = 0.f, y0 = 0.f, y1 = 0.f;
  for (int m = 0; m <= n; ++m) {
    float2 km = ks[m], vm = vs[m];
    float p = __expf(fmaf(q0, km.x, q1 * km.y));
    sm += p;
    y0 = fmaf(p, vm.x, y0);
    y1 = fmaf(p, vm.y, y1);
  }
  float inv = 1.f / sm;
  yrow[2 * n]     = __float2bfloat16(y0 * inv);
  yrow[2 * n + 1] = __float2bfloat16(y1 * inv);
}

__device__ __forceinline__ void attn_token(int r, const MegaArgs& a, char* smem) {
  float2* ks = (float2*)smem;      // 384
  float2* vs = ks + 384;           // 384
  const int t = threadIdx.x;
  const ushort2* base = (const ushort2*)(a.qkvb + (size_t)r * 2304);
  {
    ushort2 ku = base[384 + t], vu = base[768 + t];
    ks[t] = make_float2(bf2f(ku.x), bf2f(ku.y));
    vs[t] = make_float2(bf2f(vu.x), bf2f(vu.y));
    if (t < 128) {
      ushort2 ku2 = base[384 + 256 + t], vu2 = base[768 + 256 + t];
      ks[256 + t] = make_float2(bf2f(ku2.x), bf2f(ku2.y));
      vs[256 + t] = make_float2(bf2f(vu2.x), bf2f(vu2.y));
    }
  }
  __syncthreads();
  __hip_bfloat16* yrow = a.yb + (size_t)r * 768;
  attn_row(t, base, ks, vs, yrow);
  if (t < 128) attn_row(383 - t, base, ks, vs, yrow);
}

// ---------------------------------------------------------------------------
// Per-phase kernels (6 dispatches).
// ---------------------------------------------------------------------------
__global__ __launch_bounds__(256) void p0_k(MegaArgs a) {   // Tq wconv + LN1 + cnt=0
  __shared__ __align__(16) char smem[8448];
  int j = blockIdx.x;                       // 2497
  if (j < 1728)      wconv_seg(a.Wq, a.Tq, 768, 2304, j, smem);
  else if (j < 2496) ln_row(a.x, a.g1, a.be1, a.h1, j - 1728, smem);
  else if (threadIdx.x < 156) a.cnt[threadIdx.x] = 0;
}
__global__ __launch_bounds__(256) void p1_k(MegaArgs a) {   // qkv GEMM + wconv
  __shared__ __align__(16) char smem[49152];
  int j = blockIdx.x;                       // 5616 = 432 GEMM + 5184 wconv
  if (j < 432) {
    int bm = (j / 36) << 6, bn = (j % 36) << 6;
    gemm_tile<12, false, false, true, false>(
        a.h1, 768, a.Tq, 768, a.bq, nullptr, a.qkvb, 2304, bm, bn, 0, smem);
  } else {
    int jj = j - 432;
    if (jj < 576)       wconv_seg(a.Wp, a.Tp, 768, 768, jj, smem);
    else if (jj < 2880) wconv_seg(a.W1, a.T1, 768, 3072, jj - 576, smem);
    else                wconv_seg(a.W2, a.T2, 3072, 768, jj - 2880, smem);
  }
}
__global__ __launch_bounds__(256) void p2_k(MegaArgs a) {   // attention (768)
  __shared__ __align__(16) char smem[6144];
  attn_token(blockIdx.x, a, smem);
}
__global__ __launch_bounds__(256) void p3_k(MegaArgs a) {   // proj+res, LN2 by last
  __shared__ __align__(16) char smem[49152];
  __shared__ int winner;
  int j = blockIdx.x;                       // 144
  int bm = (j / 12) << 6, bn = (j % 12) << 6;
  gemm_tile<12, false, true, false, false>(
      a.yb, 768, a.Tp, 768, a.bp, a.x, a.x2, 768, bm, bn, 0, smem);
  __syncthreads();
  __threadfence();                          // release x2 tile (device scope)
  if (threadIdx.x == 0) winner = atomicAdd(&a.cnt[bm >> 6], 1);
  __syncthreads();
  if (winner == 11) {                       // 12th block for this row panel
    __threadfence();                        // acquire other blocks' x2 tiles
    ln_panel(a, bm);
  }
}
__global__ __launch_bounds__(256) void p4_k(MegaArgs a) {   // ff1 GEMM (576)
  __shared__ __align__(16) char smem[49152];
  int j = blockIdx.x;
  int bm = (j / 48) << 6, bn = (j % 48) << 6;
  gemm_tile<12, false, false, true, false>(
      a.h2, 768, a.T1, 768, a.b1, nullptr, a.ff1b, 3072, bm, bn, 0, smem);
}
__global__ __launch_bounds__(256) void p5_k(MegaArgs a) {   // ff2 splitx4, finish by last
  __shared__ __align__(16) char smem[49152];
  __shared__ int winner;
  int j = blockIdx.x;                       // 576 = 4 z x 144 tiles
  int z = j / 144, r2 = j - z * 144;
  int bm = (r2 / 12) << 6, bn = (r2 % 12) << 6;
  gemm_tile<12, false, false, false, true>(
      a.ff1b, 3072, a.T2, 3072, nullptr, nullptr,
      a.part + (size_t)z * PSTRIDE, 768, bm, bn, z * 768, smem);
  __syncthreads();
  __threadfence();                          // release partial tile
  if (threadIdx.x == 0) winner = atomicAdd(&a.cnt[12 + r2], 1);
  __syncthreads();
  if (winner == 3) {                        // 4th contributor for this tile
    __threadfence();                        // acquire other partials
    ff2_finish(a, bm, bn);
  }
}

// ---------------------------------------------------------------------------
extern "C" void kernel_launch(void* const* d_in, const int* in_sizes, int n_in,
                              void* d_out, int out_size, void* d_ws,
                              size_t ws_size, hipStream_t stream) {
  (void)in_sizes; (void)n_in; (void)out_size; (void)ws_size;
  MegaArgs a;
  a.x   = (const float*)d_in[0];
  a.Wq  = (const float*)d_in[1];
  a.bq  = (const float*)d_in[2];
  a.Wp  = (const float*)d_in[3];
  a.bp  = (const float*)d_in[4];
  a.g1  = (const float*)d_in[5];
  a.be1 = (const float*)d_in[6];
  a.g2  = (const float*)d_in[7];
  a.be2 = (const float*)d_in[8];
  a.W1  = (const float*)d_in[9];
  a.b1  = (const float*)d_in[10];
  a.W2  = (const float*)d_in[11];
  a.b2  = (const float*)d_in[12];

  char* p = (char*)d_ws;
  a.h1   = (__hip_bfloat16*)p; p += 768 * 768 * 2;
  a.qkvb = (__hip_bfloat16*)p; p += 768 * 2304 * 2;
  a.yb   = (__hip_bfloat16*)p; p += 768 * 768 * 2;
  a.x2   = (float*)p;          p += 768 * 768 * 4;
  a.h2   = (__hip_bfloat16*)p; p += 768 * 768 * 2;
  a.ff1b = (__hip_bfloat16*)p; p += 768 * 3072 * 2;
  a.Tq   = (__hip_bfloat16*)p; p += 2304 * 768 * 2;
  a.Tp   = (__hip_bfloat16*)p; p += 768 * 768 * 2;
  a.T1   = (__hip_bfloat16*)p; p += 3072 * 768 * 2;
  a.T2   = (__hip_bfloat16*)p; p += 768 * 3072 * 2;
  a.part = (float*)p;          p += 4 * 768 * 768 * 4;
  a.cnt  = (int*)p;            p += 156 * 4;
  a.out  = (float*)d_out;

  p0_k<<<2497, 256, 0, stream>>>(a);  // Tq -> bf16[N][K] + LN1 + zero counters
  p1_k<<<5616, 256, 0, stream>>>(a);  // qkv GEMM + Tp/T1/T2 wconv (hidden)
  p2_k<<<768, 256, 0, stream>>>(a);   // per-token head-axis attention
  p3_k<<<144, 256, 0, stream>>>(a);   // x2 = x + y @ Tp^T + bp; LN2 by last block
  p4_k<<<576, 256, 0, stream>>>(a);   // ff1 = h2 @ T1^T + b1
  p5_k<<<576, 256, 0, stream>>>(a);   // ff2 split-K x4 + finish by last block
}

// Round 11
// 82.866 us; speedup vs baseline: 2.7986x; 2.7986x over previous
//
#include <hip/hip_runtime.h>
#include <hip/hip_bf16.h>
#include <math.h>

// Fixed dims: B=2, T=384, C=768 -> M = 768. NH=384, HD=2. SCALE = 1/sqrt(2).
#define SCALE_QK 0.70710678118654752f
#define PSTRIDE 589824     // 768*768 (split-K partial stride, floats)

typedef __attribute__((ext_vector_type(8))) short bf16x8;   // 8 bf16 = 4 VGPRs
typedef __attribute__((ext_vector_type(4))) float floatx4;

__device__ __forceinline__ void gload16(const void* g, void* l) {
  __builtin_amdgcn_global_load_lds(
      (const __attribute__((address_space(1))) void*)g,
      (__attribute__((address_space(3))) void*)l, 16, 0, 0);
}

__device__ __forceinline__ float bf2f(unsigned short u) {
  union { float f; unsigned int i; } c; c.i = ((unsigned int)u) << 16; return c.f;
}

__device__ __forceinline__ float gelu_f(float v) {
  return 0.5f * v * (1.f + erff(v * 0.70710678118654752f));
}

struct MegaArgs {
  const float *x, *Wq, *bq, *Wp, *bp, *g1, *be1, *g2, *be2, *W1, *b1, *W2, *b2;
  __hip_bfloat16 *h1, *qkvb, *yb, *h2, *ff1b, *Tq, *Tp, *T1, *T2;
  float *x2, *part, *out;
};

// ---------------------------------------------------------------------------
// Weight transpose+convert tile: fp32 [K][N] -> bf16 [N][K], one 32x32 tile.
// ---------------------------------------------------------------------------
__device__ __forceinline__ void wconv_seg(const float* __restrict__ src,
                                          __hip_bfloat16* __restrict__ dst,
                                          int K, int N, int idx, char* smem) {
  float (*t)[33] = (float(*)[33])smem;
  int tilesN = N >> 5;
  int tk = idx / tilesN, tn = idx - tk * tilesN;
  int r = threadIdx.x >> 5, c = threadIdx.x & 31;
#pragma unroll
  for (int p = 0; p < 4; ++p)
    t[p * 8 + r][c] = src[(size_t)(tk * 32 + p * 8 + r) * N + tn * 32 + c];
  __syncthreads();
#pragma unroll
  for (int p = 0; p < 4; ++p)
    dst[(size_t)(tn * 32 + p * 8 + r) * K + tk * 32 + c] =
        __float2bfloat16(t[c][p * 8 + r]);
}

// ---------------------------------------------------------------------------
// Generic LN row (256 threads, one row): dst = LN(src; g, b) in bf16.
// ---------------------------------------------------------------------------
__device__ __forceinline__ void ln_row(const float* __restrict__ src,
                                       const float* __restrict__ g,
                                       const float* __restrict__ b,
                                       __hip_bfloat16* __restrict__ dst,
                                       int r, char* smem) {
  float* red0 = (float*)smem; float* red1 = red0 + 4;
  const float* xr = src + (size_t)r * 768;
  __hip_bfloat16* orow = dst + (size_t)r * 768;
  float vals[3]; float s = 0.f, s2 = 0.f;
#pragma unroll
  for (int p = 0; p < 3; ++p) {
    float v = xr[threadIdx.x + p * 256];
    vals[p] = v; s += v; s2 += v * v;
  }
#pragma unroll
  for (int off = 32; off > 0; off >>= 1) {
    s += __shfl_down(s, off); s2 += __shfl_down(s2, off);
  }
  int wid = threadIdx.x >> 6, lane = threadIdx.x & 63;
  if (lane == 0) { red0[wid] = s; red1[wid] = s2; }
  __syncthreads();
  if (threadIdx.x == 0) {
    red0[0] = red0[0] + red0[1] + red0[2] + red0[3];
    red1[0] = red1[0] + red1[1] + red1[2] + red1[3];
  }
  __syncthreads();
  float mean = red0[0] * (1.f / 768), var = red1[0] * (1.f / 768) - mean * mean;
  float rstd = rsqrtf(var + 1e-5f);
#pragma unroll
  for (int p = 0; p < 3; ++p) {
    int i = threadIdx.x + p * 256;
    orow[i] = __float2bfloat16((vals[p] - mean) * rstd * g[i] + b[i]);
  }
}

// ---------------------------------------------------------------------------
// bf16 MFMA GEMM tile (round-3 proven, 5x refcheck'd). 64x64, BK=64, depth-2
// pipeline over 3 LDS buffers, counted vmcnt, XOR swizzle on source+read
// (dest linear). SPLIT: raw fp32 partial (N cols); else bias (+gelu)(+res).
// ---------------------------------------------------------------------------
template <int NT, bool GELU, bool RES, bool OUT_BF16, bool SPLIT>
__device__ __forceinline__ void gemm_tile(
    const __hip_bfloat16* __restrict__ A, int ldA,
    const __hip_bfloat16* __restrict__ Bt, int ldB,
    const float* __restrict__ bias, const float* __restrict__ res,
    void* __restrict__ outp, int N, int bm, int bn, int kofe, char* lds) {
  const int tid = threadIdx.x;
  const int w = tid >> 6, l = tid & 63;

  const int sr = (w << 3) + (l >> 3);                   // 0..31
  const int swb = ((l & 7) << 4) ^ ((l >> 3) << 4);     // byte within 128B row
  const char* a0 = (const char*)(A + (size_t)(bm + sr) * ldA + kofe) + swb;
  const char* a1 = a0 + (size_t)32 * ldA * 2;
  const char* b0 = (const char*)(Bt + (size_t)(bn + sr) * ldB + kofe) + swb;
  const char* b1 = b0 + (size_t)32 * ldB * 2;
  char* dW = lds + (w << 10);

#define STAGE(buf, t) do {                     \
    char* d_ = dW + (buf) * 16384;             \
    gload16(a0 + (t) * 128, d_);               \
    gload16(a1 + (t) * 128, d_ + 4096);        \
    gload16(b0 + (t) * 128, d_ + 8192);        \
    gload16(b1 + (t) * 128, d_ + 12288);       \
  } while (0)

  const int wr = w >> 1, wc = w & 1;
  const int fr = l & 15, g = l >> 4;
  const int fsw = (fr & 7) << 4;
  int aof[2][2], bof[2][2];
#pragma unroll
  for (int i = 0; i < 2; ++i)
#pragma unroll
    for (int kk = 0; kk < 2; ++kk) {
      aof[i][kk] = (wr * 32 + i * 16 + fr) * 128 + ((kk * 64 + g * 16) ^ fsw);
      bof[i][kk] = 8192 + (wc * 32 + i * 16 + fr) * 128 +
                   ((kk * 64 + g * 16) ^ fsw);
    }

  floatx4 acc[2][2] = {};

#define COMPUTE(bufoff) do {                                          \
    const char* base_ = lds + (bufoff);                               \
    bf16x8 av_[2][2], bv_[2][2];                                      \
    _Pragma("unroll") for (int i = 0; i < 2; ++i)                     \
      _Pragma("unroll") for (int kk = 0; kk < 2; ++kk) {              \
        av_[i][kk] = *(const bf16x8*)(base_ + aof[i][kk]);            \
        bv_[i][kk] = *(const bf16x8*)(base_ + bof[i][kk]);            \
      }                                                               \
    _Pragma("unroll") for (int kk = 0; kk < 2; ++kk)                  \
      _Pragma("unroll") for (int i = 0; i < 2; ++i)                   \
        _Pragma("unroll") for (int j = 0; j < 2; ++j)                 \
          acc[i][j] = __builtin_amdgcn_mfma_f32_16x16x32_bf16(        \
              av_[i][kk], bv_[j][kk], acc[i][j], 0, 0, 0);            \
  } while (0)

  STAGE(0, 0);
  STAGE(1, 1);
  asm volatile("s_waitcnt vmcnt(4)" ::: "memory");
  __builtin_amdgcn_s_barrier();
  asm volatile("" ::: "memory");

#pragma unroll
  for (int t = 0; t < NT; ++t) {
    if (t + 2 < NT) STAGE((t + 2) % 3, t + 2);
    COMPUTE((t % 3) * 16384);
    if (t + 1 < NT) {
      if (t + 2 < NT) {
        asm volatile("s_waitcnt vmcnt(4)" ::: "memory");
      } else {
        asm volatile("s_waitcnt vmcnt(0)" ::: "memory");
      }
      __builtin_amdgcn_s_barrier();
      asm volatile("" ::: "memory");
    }
  }
#undef STAGE
#undef COMPUTE

  // C/D: col = lane&15, row = (lane>>4)*4 + reg (m89)
  const int orow0 = bm + wr * 32 + g * 4;
  const int ocol0 = bn + wc * 32 + fr;
#pragma unroll
  for (int fm = 0; fm < 2; ++fm)
#pragma unroll
    for (int fn = 0; fn < 2; ++fn) {
      int col = ocol0 + fn * 16;
      float bv = SPLIT ? 0.f : bias[col];
#pragma unroll
      for (int i = 0; i < 4; ++i) {
        int row = orow0 + fm * 16 + i;
        if (SPLIT) {
          ((float*)outp)[(size_t)row * N + col] = acc[fm][fn][i];
        } else {
          float v = acc[fm][fn][i] + bv;
          if (GELU) v = gelu_f(v);
          if (RES) v += res[(size_t)row * N + col];
          if (OUT_BF16)
            ((__hip_bfloat16*)outp)[(size_t)row * N + col] = __float2bfloat16(v);
          else
            ((float*)outp)[(size_t)row * N + col] = v;
        }
      }
    }
}

// ---------------------------------------------------------------------------
// Attention token (256 threads): rows t and 383-t (t<128) -> balanced 385
// iters/thread. Scores over head axis, causal m<=n, plain exp (bounded data).
// ---------------------------------------------------------------------------
__device__ __forceinline__ void attn_row(int n, const ushort2* base,
    const float2* ks, const float2* vs, __hip_bfloat16* yrow) {
  ushort2 qu = base[n];
  float q0 = bf2f(qu.x) * SCALE_QK, q1 = bf2f(qu.y) * SCALE_QK;
  float sm = 0.f, y0 = 0.f, y1 = 0.f;
  for (int m = 0; m <= n; ++m) {
    float2 km = ks[m], vm = vs[m];
    float p = __expf(fmaf(q0, km.x, q1 * km.y));
    sm += p;
    y0 = fmaf(p, vm.x, y0);
    y1 = fmaf(p, vm.y, y1);
  }
  float inv = 1.f / sm;
  yrow[2 * n]     = __float2bfloat16(y0 * inv);
  yrow[2 * n + 1] = __float2bfloat16(y1 * inv);
}

__device__ __forceinline__ void attn_token(int r, const MegaArgs& a, char* smem) {
  float2* ks = (float2*)smem;      // 384
  float2* vs = ks + 384;           // 384
  const int t = threadIdx.x;
  const ushort2* base = (const ushort2*)(a.qkvb + (size_t)r * 2304);
  {
    ushort2 ku = base[384 + t], vu = base[768 + t];
    ks[t] = make_float2(bf2f(ku.x), bf2f(ku.y));
    vs[t] = make_float2(bf2f(vu.x), bf2f(vu.y));
    if (t < 128) {
      ushort2 ku2 = base[384 + 256 + t], vu2 = base[768 + 256 + t];
      ks[256 + t] = make_float2(bf2f(ku2.x), bf2f(ku2.y));
      vs[256 + t] = make_float2(bf2f(vu2.x), bf2f(vu2.y));
    }
  }
  __syncthreads();
  __hip_bfloat16* yrow = a.yb + (size_t)r * 768;
  attn_row(t, base, ks, vs, yrow);
  if (t < 128) attn_row(383 - t, base, ks, vs, yrow);
}

// ---------------------------------------------------------------------------
// Final reduce: out = x2 + gelu(sum2 part + b2). idx in float4 units.
// ---------------------------------------------------------------------------
__device__ __forceinline__ void p7_elem(int idx, const MegaArgs& a) {
  int i = idx * 4;
  floatx4 s = *(const floatx4*)(a.part + i);
  s += *(const floatx4*)(a.part + PSTRIDE + i);
  int c = i - (i / 768) * 768;
  floatx4 bv = *(const floatx4*)(a.b2 + c);
  floatx4 xv = *(const floatx4*)(a.x2 + i);
  floatx4 o;
#pragma unroll
  for (int e = 0; e < 4; ++e) o[e] = xv[e] + gelu_f(s[e] + bv[e]);
  *(floatx4*)(a.out + i) = o;
}

// ---------------------------------------------------------------------------
// Per-phase kernels (8 dispatches, no device-scope fences).
// wconv placement: Tq in p0 (needed p1); Tp in p1 (needed p3);
// T1/T2 in p2 alongside compute-bound attention (needed p5/p6).
// ---------------------------------------------------------------------------
__global__ __launch_bounds__(256) void p0_k(MegaArgs a) {   // Tq wconv + LN1
  __shared__ __align__(16) char smem[8448];
  int j = blockIdx.x;                       // 2496 = 1728 + 768
  if (j < 1728) wconv_seg(a.Wq, a.Tq, 768, 2304, j, smem);
  else          ln_row(a.x, a.g1, a.be1, a.h1, j - 1728, smem);
}
__global__ __launch_bounds__(256) void p1_k(MegaArgs a) {   // qkv GEMM + Tp wconv
  __shared__ __align__(16) char smem[49152];
  int j = blockIdx.x;                       // 1008 = 432 GEMM + 576 wconv
  if (j < 432) {
    int bm = (j / 36) << 6, bn = (j % 36) << 6;
    gemm_tile<12, false, false, true, false>(
        a.h1, 768, a.Tq, 768, a.bq, nullptr, a.qkvb, 2304, bm, bn, 0, smem);
  } else {
    wconv_seg(a.Wp, a.Tp, 768, 768, j - 432, smem);
  }
}
__global__ __launch_bounds__(256) void p2_k(MegaArgs a) {   // attn + T1/T2 wconv
  __shared__ __align__(16) char smem[6144];
  int j = blockIdx.x;                       // 5376 = 768 attn + 2304 + 2304
  if (j < 768)       attn_token(j, a, smem);
  else if (j < 3072) wconv_seg(a.W1, a.T1, 768, 3072, j - 768, smem);
  else               wconv_seg(a.W2, a.T2, 3072, 768, j - 3072, smem);
}
__global__ __launch_bounds__(256) void p3_k(MegaArgs a) {   // proj+res (144)
  __shared__ __align__(16) char smem[49152];
  int j = blockIdx.x;
  int bm = (j / 12) << 6, bn = (j % 12) << 6;
  gemm_tile<12, false, true, false, false>(
      a.yb, 768, a.Tp, 768, a.bp, a.x, a.x2, 768, bm, bn, 0, smem);
}
__global__ __launch_bounds__(256) void p4_k(MegaArgs a) {   // LN2 (768)
  __shared__ __align__(16) char smem[64];
  ln_row(a.x2, a.g2, a.be2, a.h2, blockIdx.x, smem);
}
__global__ __launch_bounds__(256) void p5_k(MegaArgs a) {   // ff1 GEMM (576)
  __shared__ __align__(16) char smem[49152];
  int j = blockIdx.x;
  int bm = (j / 48) << 6, bn = (j % 48) << 6;
  gemm_tile<12, false, false, true, false>(
      a.h2, 768, a.T1, 768, a.b1, nullptr, a.ff1b, 3072, bm, bn, 0, smem);
}
__global__ __launch_bounds__(256) void p6_k(MegaArgs a) {   // ff2 splitx2 (288)
  __shared__ __align__(16) char smem[49152];
  int j = blockIdx.x;                       // 288 = 2 z x 144 tiles
  int z = j / 144, r2 = j - z * 144;
  int bm = (r2 / 12) << 6, bn = (r2 % 12) << 6;
  gemm_tile<24, false, false, false, true>(
      a.ff1b, 3072, a.T2, 3072, nullptr, nullptr,
      a.part + (size_t)z * PSTRIDE, 768, bm, bn, z * 1536, smem);
}
__global__ __launch_bounds__(256) void p7_k(MegaArgs a) {   // reduce+gelu+res
  p7_elem(blockIdx.x * 256 + threadIdx.x, a);
}

// ---------------------------------------------------------------------------
extern "C" void kernel_launch(void* const* d_in, const int* in_sizes, int n_in,
                              void* d_out, int out_size, void* d_ws,
                              size_t ws_size, hipStream_t stream) {
  (void)in_sizes; (void)n_in; (void)out_size; (void)ws_size;
  MegaArgs a;
  a.x   = (const float*)d_in[0];
  a.Wq  = (const float*)d_in[1];
  a.bq  = (const float*)d_in[2];
  a.Wp  = (const float*)d_in[3];
  a.bp  = (const float*)d_in[4];
  a.g1  = (const float*)d_in[5];
  a.be1 = (const float*)d_in[6];
  a.g2  = (const float*)d_in[7];
  a.be2 = (const float*)d_in[8];
  a.W1  = (const float*)d_in[9];
  a.b1  = (const float*)d_in[10];
  a.W2  = (const float*)d_in[11];
  a.b2  = (const float*)d_in[12];

  char* p = (char*)d_ws;
  a.h1   = (__hip_bfloat16*)p; p += 768 * 768 * 2;
  a.qkvb = (__hip_bfloat16*)p; p += 768 * 2304 * 2;
  a.yb   = (__hip_bfloat16*)p; p += 768 * 768 * 2;
  a.x2   = (float*)p;          p += 768 * 768 * 4;
  a.h2   = (__hip_bfloat16*)p; p += 768 * 768 * 2;
  a.ff1b = (__hip_bfloat16*)p; p += 768 * 3072 * 2;
  a.Tq   = (__hip_bfloat16*)p; p += 2304 * 768 * 2;
  a.Tp   = (__hip_bfloat16*)p; p += 768 * 768 * 2;
  a.T1   = (__hip_bfloat16*)p; p += 3072 * 768 * 2;
  a.T2   = (__hip_bfloat16*)p; p += 768 * 3072 * 2;
  a.part = (float*)p;          p += 2 * 768 * 768 * 4;
  a.out  = (float*)d_out;

  p0_k<<<2496, 256, 0, stream>>>(a);  // Tq -> bf16[N][K] + LN1
  p1_k<<<1008, 256, 0, stream>>>(a);  // qkv GEMM + Tp wconv
  p2_k<<<5376, 256, 0, stream>>>(a);  // attention + T1/T2 wconv (hidden)
  p3_k<<<144, 256, 0, stream>>>(a);   // x2 = x + y @ Tp^T + bp
  p4_k<<<768, 256, 0, stream>>>(a);   // h2 = LN2(x2)
  p5_k<<<576, 256, 0, stream>>>(a);   // ff1 = h2 @ T1^T + b1
  p6_k<<<288, 256, 0, stream>>>(a);   // ff2 split-K x2 -> part
  p7_k<<<576, 256, 0, stream>>>(a);   // out = x2 + gelu(sum part + b2)
}